// Round 1
// baseline (478.532 us; speedup 1.0000x reference)
//
#include <hip/hip_runtime.h>
#include <math.h>

#define NB 4
#define NS 1024
#define DM 512
#define NH 8
#define DEPTH 64
#define NBH (NB*NH)

// ws offsets (in floats)
#define OFF_QH   0
#define OFF_KH   (2*1024*1024)
#define OFF_VH   (4*1024*1024)
#define OFF_CTX  (6*1024*1024)
#define OFF_PMAX (8*1024*1024)
#define OFF_MBH  (OFF_PMAX + 8192)
#define OFF_PSUM (OFF_MBH + 64)
#define OFF_SINV (OFF_PSUM + 8192)

// ---------------- projection GEMM: X(4096x512) @ W(512x512) + b -> split heads
__global__ __launch_bounds__(256) void k_proj(
    const float* __restrict__ q, const float* __restrict__ k, const float* __restrict__ v,
    const float* __restrict__ wq, const float* __restrict__ bq,
    const float* __restrict__ wk, const float* __restrict__ bk,
    const float* __restrict__ wv, const float* __restrict__ bv,
    float* __restrict__ ws)
{
    const float* X; const float* W; const float* bias; float* out;
    if (blockIdx.z == 0)      { X = q; W = wq; bias = bq; out = ws + OFF_QH; }
    else if (blockIdx.z == 1) { X = k; W = wk; bias = bk; out = ws + OFF_KH; }
    else                      { X = v; W = wv; bias = bv; out = ws + OFF_VH; }

    __shared__ float as[64][65];
    __shared__ float bs[64][65];
    int tid = threadIdx.x;
    int tx = tid & 15, ty = tid >> 4;
    int m0 = blockIdx.y * 64;
    int n0 = blockIdx.x * 64;
    float acc[4][4] = {};

    for (int kk = 0; kk < DM; kk += 64) {
        for (int idx = tid; idx < 4096; idx += 256) {
            int r = idx >> 6, c = idx & 63;
            as[r][c] = X[(size_t)(m0 + r) * DM + kk + c];
            bs[r][c] = W[(size_t)(kk + r) * DM + n0 + c];
        }
        __syncthreads();
        for (int kq = 0; kq < 64; ++kq) {
            float a[4], bb[4];
            #pragma unroll
            for (int i = 0; i < 4; ++i) a[i] = as[ty + 16*i][kq];
            #pragma unroll
            for (int j = 0; j < 4; ++j) bb[j] = bs[kq][tx + 16*j];
            #pragma unroll
            for (int i = 0; i < 4; ++i)
                #pragma unroll
                for (int j = 0; j < 4; ++j) acc[i][j] += a[i] * bb[j];
        }
        __syncthreads();
    }

    #pragma unroll
    for (int i = 0; i < 4; ++i) {
        int m = m0 + ty + 16*i;
        int b = m >> 10, s = m & 1023;
        #pragma unroll
        for (int j = 0; j < 4; ++j) {
            int n = n0 + tx + 16*j;
            int h = n >> 6, d = n & 63;
            out[(((size_t)(b*NH + h))*NS + s)*DEPTH + d] = acc[i][j] + bias[n];
        }
    }
}

// ---------------- scores/logits tile; PASS 0: block max partials; PASS 1: e=exp(l-m), write, sum partials
template<int PASS>
__global__ __launch_bounds__(256) void k_scores(
    float* __restrict__ ws,
    const float* __restrict__ table_hb, const float* __restrict__ table_pi,
    const float* __restrict__ mask,
    const float* __restrict__ aug_hb, const float* __restrict__ aug_pi,
    const float* __restrict__ aug_at, const int* __restrict__ bnum,
    float* __restrict__ attn_out)
{
    int bh = blockIdx.z;
    int b  = bh >> 3;
    int i0 = blockIdx.y * 64;
    int j0 = blockIdx.x * 64;
    const float* kh = ws + OFF_KH + (size_t)bh * NS * DEPTH;
    const float* qh = ws + OFF_QH + (size_t)bh * NS * DEPTH;

    __shared__ float ksb[64][65];
    __shared__ float qsb[64][65];
    __shared__ float red[256];

    int tid = threadIdx.x;
    int tx = tid & 15, ty = tid >> 4;

    for (int idx = tid; idx < 4096; idx += 256) {
        int r = idx >> 6, c = idx & 63;
        ksb[r][c] = kh[(size_t)(i0 + r) * DEPTH + c];
        qsb[r][c] = qh[(size_t)(j0 + r) * DEPTH + c];
    }
    __syncthreads();

    float acc[4][4] = {};
    for (int d = 0; d < 64; ++d) {
        float a[4], bb[4];
        #pragma unroll
        for (int i = 0; i < 4; ++i) a[i] = ksb[ty + 16*i][d];
        #pragma unroll
        for (int j = 0; j < 4; ++j) bb[j] = qsb[tx + 16*j][d];
        #pragma unroll
        for (int i = 0; i < 4; ++i)
            #pragma unroll
            for (int j = 0; j < 4; ++j) acc[i][j] += a[i] * bb[j];
    }

    int bn = bnum[0];
    float at = aug_at[bn], hb = aug_hb[bn], pi = aug_pi[bn];
    float mbh = 0.f;
    if (PASS == 1) mbh = ws[OFF_MBH + bh];

    float local = (PASS == 0) ? -INFINITY : 0.f;

    #pragma unroll
    for (int i = 0; i < 4; ++i) {
        int gi = i0 + ty + 16*i;
        #pragma unroll
        for (int j = 0; j < 4; ++j) {
            int gj = j0 + tx + 16*j;
            float mv  = mask[((size_t)b * NS + gi) * NS + gj];
            float thb = table_hb[(size_t)gi * NS + gj];
            float tpi = table_pi[(size_t)gi * NS + gj];
            float l = (acc[i][j] * 0.125f + mv * (-1e9f)) * at + hb * thb + pi * tpi;
            if (PASS == 0) {
                local = fmaxf(local, l);
            } else {
                float e = expf(l - mbh);
                attn_out[((size_t)bh * NS + gi) * NS + gj] = e;
                local += e;
            }
        }
    }

    // block reduce
    red[tid] = local;
    __syncthreads();
    for (int s2 = 128; s2 > 0; s2 >>= 1) {
        if (tid < s2) {
            if (PASS == 0) red[tid] = fmaxf(red[tid], red[tid + s2]);
            else           red[tid] = red[tid] + red[tid + s2];
        }
        __syncthreads();
    }
    if (tid == 0) {
        int slot = bh * 256 + blockIdx.y * 16 + blockIdx.x;
        if (PASS == 0) ws[OFF_PMAX + slot] = red[0];
        else           ws[OFF_PSUM + slot] = red[0];
    }
}

// ---------------- small reductions over the 256 block partials per (b,h)
__global__ __launch_bounds__(256) void k_reduce_max(float* __restrict__ ws)
{
    int bh = blockIdx.x, tid = threadIdx.x;
    __shared__ float red[256];
    red[tid] = ws[OFF_PMAX + bh * 256 + tid];
    __syncthreads();
    for (int s2 = 128; s2 > 0; s2 >>= 1) {
        if (tid < s2) red[tid] = fmaxf(red[tid], red[tid + s2]);
        __syncthreads();
    }
    if (tid == 0) ws[OFF_MBH + bh] = red[0];
}

__global__ __launch_bounds__(256) void k_reduce_sum(float* __restrict__ ws)
{
    int bh = blockIdx.x, tid = threadIdx.x;
    __shared__ float red[256];
    red[tid] = ws[OFF_PSUM + bh * 256 + tid];
    __syncthreads();
    for (int s2 = 128; s2 > 0; s2 >>= 1) {
        if (tid < s2) red[tid] += red[tid + s2];
        __syncthreads();
    }
    if (tid == 0) ws[OFF_SINV + bh] = 1.0f / red[0];
}

// ---------------- ctx = (e/sum) @ vh, fused attn normalization write-back
__global__ __launch_bounds__(256) void k_ctx(
    float* __restrict__ attn, float* __restrict__ ws)
{
    int bh = blockIdx.y;
    int i0 = blockIdx.x * 64;
    int b = bh >> 3, h = bh & 7;
    const float* vh = ws + OFF_VH + (size_t)bh * NS * DEPTH;
    float inv = ws[OFF_SINV + bh];
    float* arow = attn + ((size_t)bh * NS + i0) * NS;

    __shared__ float es[64][65];
    __shared__ float vs[64][65];
    int tid = threadIdx.x;
    int tx = tid & 15, ty = tid >> 4;
    float acc[4][4] = {};

    for (int j0 = 0; j0 < NS; j0 += 64) {
        for (int idx = tid; idx < 4096; idx += 256) {
            int r = idx >> 6, c = idx & 63;
            float e = arow[(size_t)r * NS + j0 + c];
            es[r][c] = e;
            arow[(size_t)r * NS + j0 + c] = e * inv;   // normalized attn out
            vs[r][c] = vh[(size_t)(j0 + r) * DEPTH + c];
        }
        __syncthreads();
        for (int jq = 0; jq < 64; ++jq) {
            float a[4], bb[4];
            #pragma unroll
            for (int i = 0; i < 4; ++i) a[i] = es[ty + 16*i][jq];
            #pragma unroll
            for (int j = 0; j < 4; ++j) bb[j] = vs[jq][tx + 16*j];
            #pragma unroll
            for (int i = 0; i < 4; ++i)
                #pragma unroll
                for (int j = 0; j < 4; ++j) acc[i][j] += a[i] * bb[j];
        }
        __syncthreads();
    }

    #pragma unroll
    for (int i = 0; i < 4; ++i) {
        int gi = i0 + ty + 16*i;
        #pragma unroll
        for (int j = 0; j < 4; ++j) {
            int d = tx + 16*j;
            ws[OFF_CTX + ((size_t)b * NS + gi) * DM + h * DEPTH + d] = acc[i][j] * inv;
        }
    }
}

// ---------------- out = ctx(4096x512) @ wo(512x512) + b
__global__ __launch_bounds__(256) void k_out(
    const float* __restrict__ ws, const float* __restrict__ wo,
    const float* __restrict__ bo, float* __restrict__ outp)
{
    const float* X = ws + OFF_CTX;
    __shared__ float as[64][65];
    __shared__ float bs[64][65];
    int tid = threadIdx.x;
    int tx = tid & 15, ty = tid >> 4;
    int m0 = blockIdx.y * 64;
    int n0 = blockIdx.x * 64;
    float acc[4][4] = {};

    for (int kk = 0; kk < DM; kk += 64) {
        for (int idx = tid; idx < 4096; idx += 256) {
            int r = idx >> 6, c = idx & 63;
            as[r][c] = X[(size_t)(m0 + r) * DM + kk + c];
            bs[r][c] = wo[(size_t)(kk + r) * DM + n0 + c];
        }
        __syncthreads();
        for (int kq = 0; kq < 64; ++kq) {
            float a[4], bb[4];
            #pragma unroll
            for (int i = 0; i < 4; ++i) a[i] = as[ty + 16*i][kq];
            #pragma unroll
            for (int j = 0; j < 4; ++j) bb[j] = bs[kq][tx + 16*j];
            #pragma unroll
            for (int i = 0; i < 4; ++i)
                #pragma unroll
                for (int j = 0; j < 4; ++j) acc[i][j] += a[i] * bb[j];
        }
        __syncthreads();
    }

    #pragma unroll
    for (int i = 0; i < 4; ++i) {
        int m = m0 + ty + 16*i;
        #pragma unroll
        for (int j = 0; j < 4; ++j) {
            int n = n0 + tx + 16*j;
            outp[(size_t)m * DM + n] = acc[i][j] + bo[n];
        }
    }
}

extern "C" void kernel_launch(void* const* d_in, const int* in_sizes, int n_in,
                              void* d_out, int out_size, void* d_ws, size_t ws_size,
                              hipStream_t stream)
{
    const float* v    = (const float*)d_in[0];
    const float* q    = (const float*)d_in[1];
    const float* k    = (const float*)d_in[2];
    const float* wq_w = (const float*)d_in[3];
    const float* wq_b = (const float*)d_in[4];
    const float* wk_w = (const float*)d_in[5];
    const float* wk_b = (const float*)d_in[6];
    const float* wv_w = (const float*)d_in[7];
    const float* wv_b = (const float*)d_in[8];
    const float* wo_w = (const float*)d_in[9];
    const float* wo_b = (const float*)d_in[10];
    const float* aug_hb = (const float*)d_in[11];
    const float* aug_pi = (const float*)d_in[12];
    const float* aug_at = (const float*)d_in[13];
    const float* t_hb   = (const float*)d_in[14];
    const float* t_pi   = (const float*)d_in[15];
    const float* mask   = (const float*)d_in[16];
    const int*   bnum   = (const int*)d_in[17];

    float* ws   = (float*)d_ws;
    float* outp = (float*)d_out;                       // (B,S,DM) = 2,097,152 floats
    float* attn = (float*)d_out + (size_t)NB*NS*DM;    // (B,H,S,S)

    // 1. projections
    hipLaunchKernelGGL(k_proj, dim3(8, 64, 3), dim3(256), 0, stream,
                       q, k, v, wq_w, wq_b, wk_w, wk_b, wv_w, wv_b, ws);
    // 2. logits max pass
    hipLaunchKernelGGL((k_scores<0>), dim3(16, 16, NBH), dim3(256), 0, stream,
                       ws, t_hb, t_pi, mask, aug_hb, aug_pi, aug_at, bnum, attn);
    hipLaunchKernelGGL(k_reduce_max, dim3(NBH), dim3(256), 0, stream, ws);
    // 3. exp pass (writes unnormalized e into attn region) + sums
    hipLaunchKernelGGL((k_scores<1>), dim3(16, 16, NBH), dim3(256), 0, stream,
                       ws, t_hb, t_pi, mask, aug_hb, aug_pi, aug_at, bnum, attn);
    hipLaunchKernelGGL(k_reduce_sum, dim3(NBH), dim3(256), 0, stream, ws);
    // 4. ctx GEMM + attn normalization
    hipLaunchKernelGGL(k_ctx, dim3(16, NBH), dim3(256), 0, stream, attn, ws);
    // 5. output projection
    hipLaunchKernelGGL(k_out, dim3(8, 64), dim3(256), 0, stream, ws, wo_w, wo_b, outp);
}

// Round 2
// 392.081 us; speedup vs baseline: 1.2205x; 1.2205x over previous
//
#include <hip/hip_runtime.h>
#include <math.h>

#define NS 1024
#define DM 512
#define NH 8
#define DEPTH 64

// ws offsets (floats)
#define OFF_QH   0
#define OFF_KH   (2*1024*1024)
#define OFF_VH   (4*1024*1024)
#define OFF_CTX  (6*1024*1024)
#define OFF_PART (8*1024*1024)
#define OFF_SINV (OFF_PART + 4096)

// ---------------- QKV projection GEMM: X(4096x512)@W(512x512)+b -> split heads
// 128(M)x64(N) tile, BK=32, 8x4 per thread, all inner LDS reads are b128 row-uniform.
__global__ __launch_bounds__(256) void k_proj(
    const float* __restrict__ q, const float* __restrict__ k, const float* __restrict__ v,
    const float* __restrict__ wq, const float* __restrict__ bq,
    const float* __restrict__ wk, const float* __restrict__ bk,
    const float* __restrict__ wv, const float* __restrict__ bv,
    float* __restrict__ ws)
{
    const float *X, *W, *bias; float* out;
    if (blockIdx.z == 0)      { X=q; W=wq; bias=bq; out=ws+OFF_QH; }
    else if (blockIdx.z == 1) { X=k; W=wk; bias=bk; out=ws+OFF_KH; }
    else                      { X=v; W=wv; bias=bv; out=ws+OFF_VH; }

    __shared__ float As[32][132];   // [k][m] transposed
    __shared__ float Bs[32][68];    // [k][n]
    const int tid = threadIdx.x;
    const int tx = tid & 15, ty = tid >> 4;
    const int m0 = blockIdx.y * 128, n0 = blockIdx.x * 64;

    float acc[8][4] = {};
    for (int kk = 0; kk < DM; kk += 32) {
        #pragma unroll
        for (int l = 0; l < 4; ++l) {
            const int idx = tid + l*256;
            const int m = idx >> 3, c4 = idx & 7;
            const float4 f = *(const float4*)(X + (size_t)(m0+m)*DM + kk + c4*4);
            As[c4*4+0][m] = f.x; As[c4*4+1][m] = f.y;
            As[c4*4+2][m] = f.z; As[c4*4+3][m] = f.w;
        }
        #pragma unroll
        for (int l = 0; l < 2; ++l) {
            const int idx = tid + l*256;
            const int r = idx >> 4, c4 = idx & 15;
            *(float4*)&Bs[r][c4*4] = *(const float4*)(W + (size_t)(kk+r)*DM + n0 + c4*4);
        }
        __syncthreads();
        #pragma unroll
        for (int kq = 0; kq < 32; ++kq) {
            const float4 a0 = *(const float4*)&As[kq][ty*4];
            const float4 a1 = *(const float4*)&As[kq][64 + ty*4];
            const float4 b0 = *(const float4*)&Bs[kq][tx*4];
            const float av[8] = {a0.x,a0.y,a0.z,a0.w,a1.x,a1.y,a1.z,a1.w};
            const float bw[4] = {b0.x,b0.y,b0.z,b0.w};
            #pragma unroll
            for (int i = 0; i < 8; ++i)
                #pragma unroll
                for (int j = 0; j < 4; ++j)
                    acc[i][j] = fmaf(av[i], bw[j], acc[i][j]);
        }
        __syncthreads();
    }
    const int h = n0 >> 6;                 // n0 is 64-aligned: whole tile in one head
    const float4 b4 = *(const float4*)(bias + n0 + tx*4);
    #pragma unroll
    for (int i = 0; i < 8; ++i) {
        const int m = m0 + (i>>2)*64 + ty*4 + (i&3);
        const int bb = m >> 10, s = m & 1023;
        float4 o;
        o.x = acc[i][0]+b4.x; o.y = acc[i][1]+b4.y;
        o.z = acc[i][2]+b4.z; o.w = acc[i][3]+b4.w;
        *(float4*)(out + (((size_t)(bb*NH + h))*NS + s)*DEPTH + tx*4) = o;
    }
}

// ---------------- pass 1: S = K.Q^T tile (128x128), e = exp(logits), partial sums only
__global__ __launch_bounds__(256) void k_sumexp(
    float* __restrict__ ws,
    const float* __restrict__ t_hb, const float* __restrict__ t_pi,
    const float* __restrict__ mask,
    const float* __restrict__ aug_hb, const float* __restrict__ aug_pi,
    const float* __restrict__ aug_at, const int* __restrict__ bnum)
{
    __shared__ float Ks[64][132];   // [d][i]
    __shared__ float Qs[64][132];   // [d][j]
    __shared__ float red[256];
    const int bh = blockIdx.z, b = bh >> 3;
    const int i0 = blockIdx.y * 128, j0 = blockIdx.x * 128;
    const float* kh = ws + OFF_KH + (size_t)bh*NS*DEPTH;
    const float* qh = ws + OFF_QH + (size_t)bh*NS*DEPTH;
    const int tid = threadIdx.x, tx = tid & 15, ty = tid >> 4;

    #pragma unroll
    for (int l = 0; l < 8; ++l) {
        const int idx = tid + l*256;
        const int r = idx >> 4, d4 = idx & 15;
        const float4 fk = *(const float4*)(kh + (size_t)(i0+r)*DEPTH + d4*4);
        Ks[d4*4+0][r]=fk.x; Ks[d4*4+1][r]=fk.y; Ks[d4*4+2][r]=fk.z; Ks[d4*4+3][r]=fk.w;
        const float4 fq = *(const float4*)(qh + (size_t)(j0+r)*DEPTH + d4*4);
        Qs[d4*4+0][r]=fq.x; Qs[d4*4+1][r]=fq.y; Qs[d4*4+2][r]=fq.z; Qs[d4*4+3][r]=fq.w;
    }
    __syncthreads();

    float acc[8][8] = {};
    #pragma unroll
    for (int d = 0; d < 64; ++d) {
        const float4 a0 = *(const float4*)&Ks[d][ty*4];
        const float4 a1 = *(const float4*)&Ks[d][64+ty*4];
        const float4 b0 = *(const float4*)&Qs[d][tx*4];
        const float4 b1 = *(const float4*)&Qs[d][64+tx*4];
        const float av[8] = {a0.x,a0.y,a0.z,a0.w,a1.x,a1.y,a1.z,a1.w};
        const float bw[8] = {b0.x,b0.y,b0.z,b0.w,b1.x,b1.y,b1.z,b1.w};
        #pragma unroll
        for (int i = 0; i < 8; ++i)
            #pragma unroll
            for (int j = 0; j < 8; ++j)
                acc[i][j] = fmaf(av[i], bw[j], acc[i][j]);
    }

    const int bn = bnum[0];
    const float at = aug_at[bn], hb = aug_hb[bn], pi = aug_pi[bn];
    float local = 0.f;
    #pragma unroll
    for (int i = 0; i < 8; ++i) {
        const int gi = i0 + (i>>2)*64 + ty*4 + (i&3);
        const size_t mrow = ((size_t)b*NS + gi)*NS;
        const size_t trow = (size_t)gi*NS;
        #pragma unroll
        for (int cb = 0; cb < 2; ++cb) {
            const int gj = j0 + cb*64 + tx*4;
            const float4 m4 = *(const float4*)(mask + mrow + gj);
            const float4 h4 = *(const float4*)(t_hb + trow + gj);
            const float4 p4 = *(const float4*)(t_pi + trow + gj);
            const float mm[4] = {m4.x,m4.y,m4.z,m4.w};
            const float hh[4] = {h4.x,h4.y,h4.z,h4.w};
            const float pp[4] = {p4.x,p4.y,p4.z,p4.w};
            #pragma unroll
            for (int j = 0; j < 4; ++j) {
                const float lg = (acc[i][cb*4+j]*0.125f + mm[j]*(-1e9f))*at + hb*hh[j] + pi*pp[j];
                local += __expf(lg);
            }
        }
    }
    red[tid] = local;
    __syncthreads();
    for (int s2 = 128; s2 > 0; s2 >>= 1) {
        if (tid < s2) red[tid] += red[tid + s2];
        __syncthreads();
    }
    if (tid == 0) ws[OFF_PART + bh*64 + blockIdx.y*8 + blockIdx.x] = red[0];
}

// ---------------- reduce 64 partials per (b,h) -> 1/sum
__global__ __launch_bounds__(64) void k_rsum(float* __restrict__ ws)
{
    float v = ws[OFF_PART + blockIdx.x*64 + threadIdx.x];
    #pragma unroll
    for (int o = 32; o > 0; o >>= 1) v += __shfl_down(v, o);
    if (threadIdx.x == 0) ws[OFF_SINV + blockIdx.x] = 1.0f / v;
}

// ---------------- pass 2 (fused): recompute S tile, e*inv -> attn write + PV GEMM -> ctx
__global__ __launch_bounds__(256) void k_fused(
    float* __restrict__ ws,
    const float* __restrict__ t_hb, const float* __restrict__ t_pi,
    const float* __restrict__ mask,
    const float* __restrict__ aug_hb, const float* __restrict__ aug_pi,
    const float* __restrict__ aug_at, const int* __restrict__ bnum,
    float* __restrict__ attn)
{
    __shared__ float Ks[64][68];   // [d][i]  (i-tile of 64 rows, resident whole block)
    __shared__ float Qs[64][68];   // [d][j]
    __shared__ float Vs[64][68];   // [j][d]
    __shared__ float Es[64][68];   // [j][i]  normalized e, transposed for PV
    const int bh = blockIdx.y, b = bh >> 3, h = bh & 7;
    const int i0 = blockIdx.x * 64;
    const float* kh = ws + OFF_KH + (size_t)bh*NS*DEPTH;
    const float* qh = ws + OFF_QH + (size_t)bh*NS*DEPTH;
    const float* vh = ws + OFF_VH + (size_t)bh*NS*DEPTH;
    const float inv = ws[OFF_SINV + bh];
    const int tid = threadIdx.x, tx = tid & 15, ty = tid >> 4;
    const int bn = bnum[0];
    const float at = aug_at[bn], hbb = aug_hb[bn], pii = aug_pi[bn];

    #pragma unroll
    for (int l = 0; l < 4; ++l) {
        const int idx = tid + l*256;
        const int r = idx >> 4, d4 = idx & 15;
        const float4 fk = *(const float4*)(kh + (size_t)(i0+r)*DEPTH + d4*4);
        Ks[d4*4+0][r]=fk.x; Ks[d4*4+1][r]=fk.y; Ks[d4*4+2][r]=fk.z; Ks[d4*4+3][r]=fk.w;
    }

    float ctx[4][4] = {};
    for (int j0 = 0; j0 < NS; j0 += 64) {
        #pragma unroll
        for (int l = 0; l < 4; ++l) {
            const int idx = tid + l*256;
            const int r = idx >> 4, d4 = idx & 15;
            const float4 fq = *(const float4*)(qh + (size_t)(j0+r)*DEPTH + d4*4);
            Qs[d4*4+0][r]=fq.x; Qs[d4*4+1][r]=fq.y; Qs[d4*4+2][r]=fq.z; Qs[d4*4+3][r]=fq.w;
            *(float4*)&Vs[r][d4*4] = *(const float4*)(vh + (size_t)(j0+r)*DEPTH + d4*4);
        }
        __syncthreads();   // Qs/Vs (and Ks on first iter) visible

        float s[4][4] = {};
        #pragma unroll
        for (int d = 0; d < 64; ++d) {
            const float4 a   = *(const float4*)&Ks[d][ty*4];
            const float4 bq4 = *(const float4*)&Qs[d][tx*4];
            const float av[4] = {a.x,a.y,a.z,a.w};
            const float bw[4] = {bq4.x,bq4.y,bq4.z,bq4.w};
            #pragma unroll
            for (int i = 0; i < 4; ++i)
                #pragma unroll
                for (int j = 0; j < 4; ++j)
                    s[i][j] = fmaf(av[i], bw[j], s[i][j]);
        }

        float en[4][4];
        #pragma unroll
        for (int i = 0; i < 4; ++i) {
            const int gi = i0 + ty*4 + i;
            const size_t mrow = ((size_t)b*NS + gi)*NS;
            const size_t trow = (size_t)gi*NS;
            const int gj = j0 + tx*4;
            const float4 m4 = *(const float4*)(mask + mrow + gj);
            const float4 h4 = *(const float4*)(t_hb + trow + gj);
            const float4 p4 = *(const float4*)(t_pi + trow + gj);
            const float mm[4] = {m4.x,m4.y,m4.z,m4.w};
            const float hh[4] = {h4.x,h4.y,h4.z,h4.w};
            const float pp[4] = {p4.x,p4.y,p4.z,p4.w};
            float4 o;
            #pragma unroll
            for (int j = 0; j < 4; ++j) {
                const float lg = (s[i][j]*0.125f + mm[j]*(-1e9f))*at + hbb*hh[j] + pii*pp[j];
                en[i][j] = __expf(lg) * inv;
            }
            o.x = en[i][0]; o.y = en[i][1]; o.z = en[i][2]; o.w = en[i][3];
            *(float4*)(attn + ((size_t)bh*NS + gi)*NS + gj) = o;   // final normalized attn
        }
        // E transposed into LDS for the PV contraction (b128 along i)
        #pragma unroll
        for (int j = 0; j < 4; ++j) {
            float4 e4;
            e4.x = en[0][j]; e4.y = en[1][j]; e4.z = en[2][j]; e4.w = en[3][j];
            *(float4*)&Es[tx*4+j][ty*4] = e4;
        }
        __syncthreads();   // Es visible

        #pragma unroll
        for (int jj = 0; jj < 64; ++jj) {
            const float4 a  = *(const float4*)&Es[jj][ty*4];
            const float4 vv = *(const float4*)&Vs[jj][tx*4];
            const float av[4] = {a.x,a.y,a.z,a.w};
            const float vw[4] = {vv.x,vv.y,vv.z,vv.w};
            #pragma unroll
            for (int i = 0; i < 4; ++i)
                #pragma unroll
                for (int dd = 0; dd < 4; ++dd)
                    ctx[i][dd] = fmaf(av[i], vw[dd], ctx[i][dd]);
        }
        __syncthreads();   // protect Qs/Vs/Es before next iteration's stores
    }

    #pragma unroll
    for (int i = 0; i < 4; ++i) {
        const int gi = i0 + ty*4 + i;
        float4 o;
        o.x = ctx[i][0]; o.y = ctx[i][1]; o.z = ctx[i][2]; o.w = ctx[i][3];
        *(float4*)(ws + OFF_CTX + ((size_t)b*NS + gi)*DM + h*DEPTH + tx*4) = o;
    }
}

// ---------------- out = ctx(4096x512) @ wo + b
__global__ __launch_bounds__(256) void k_out(
    const float* __restrict__ ws_c, const float* __restrict__ wo,
    const float* __restrict__ bo, float* __restrict__ outp)
{
    __shared__ float As[32][132];
    __shared__ float Bs[32][68];
    const int tid = threadIdx.x, tx = tid & 15, ty = tid >> 4;
    const int m0 = blockIdx.y * 128, n0 = blockIdx.x * 64;
    const float* X = ws_c + OFF_CTX;

    float acc[8][4] = {};
    for (int kk = 0; kk < DM; kk += 32) {
        #pragma unroll
        for (int l = 0; l < 4; ++l) {
            const int idx = tid + l*256;
            const int m = idx >> 3, c4 = idx & 7;
            const float4 f = *(const float4*)(X + (size_t)(m0+m)*DM + kk + c4*4);
            As[c4*4+0][m] = f.x; As[c4*4+1][m] = f.y;
            As[c4*4+2][m] = f.z; As[c4*4+3][m] = f.w;
        }
        #pragma unroll
        for (int l = 0; l < 2; ++l) {
            const int idx = tid + l*256;
            const int r = idx >> 4, c4 = idx & 15;
            *(float4*)&Bs[r][c4*4] = *(const float4*)(wo + (size_t)(kk+r)*DM + n0 + c4*4);
        }
        __syncthreads();
        #pragma unroll
        for (int kq = 0; kq < 32; ++kq) {
            const float4 a0 = *(const float4*)&As[kq][ty*4];
            const float4 a1 = *(const float4*)&As[kq][64 + ty*4];
            const float4 b0 = *(const float4*)&Bs[kq][tx*4];
            const float av[8] = {a0.x,a0.y,a0.z,a0.w,a1.x,a1.y,a1.z,a1.w};
            const float bw[4] = {b0.x,b0.y,b0.z,b0.w};
            #pragma unroll
            for (int i = 0; i < 8; ++i)
                #pragma unroll
                for (int j = 0; j < 4; ++j)
                    acc[i][j] = fmaf(av[i], bw[j], acc[i][j]);
        }
        __syncthreads();
    }
    const float4 b4 = *(const float4*)(bo + n0 + tx*4);
    #pragma unroll
    for (int i = 0; i < 8; ++i) {
        const int m = m0 + (i>>2)*64 + ty*4 + (i&3);
        float4 o;
        o.x = acc[i][0]+b4.x; o.y = acc[i][1]+b4.y;
        o.z = acc[i][2]+b4.z; o.w = acc[i][3]+b4.w;
        *(float4*)(outp + (size_t)m*DM + n0 + tx*4) = o;
    }
}

extern "C" void kernel_launch(void* const* d_in, const int* in_sizes, int n_in,
                              void* d_out, int out_size, void* d_ws, size_t ws_size,
                              hipStream_t stream)
{
    const float* v    = (const float*)d_in[0];
    const float* q    = (const float*)d_in[1];
    const float* k    = (const float*)d_in[2];
    const float* wq_w = (const float*)d_in[3];
    const float* wq_b = (const float*)d_in[4];
    const float* wk_w = (const float*)d_in[5];
    const float* wk_b = (const float*)d_in[6];
    const float* wv_w = (const float*)d_in[7];
    const float* wv_b = (const float*)d_in[8];
    const float* wo_w = (const float*)d_in[9];
    const float* wo_b = (const float*)d_in[10];
    const float* aug_hb = (const float*)d_in[11];
    const float* aug_pi = (const float*)d_in[12];
    const float* aug_at = (const float*)d_in[13];
    const float* t_hb   = (const float*)d_in[14];
    const float* t_pi   = (const float*)d_in[15];
    const float* mask   = (const float*)d_in[16];
    const int*   bnum   = (const int*)d_in[17];

    float* ws   = (float*)d_ws;
    float* outp = (float*)d_out;
    float* attn = (float*)d_out + (size_t)4*NS*DM;

    hipLaunchKernelGGL(k_proj, dim3(8, 32, 3), dim3(256), 0, stream,
                       q, k, v, wq_w, wq_b, wk_w, wk_b, wv_w, wv_b, ws);
    hipLaunchKernelGGL(k_sumexp, dim3(8, 8, 32), dim3(256), 0, stream,
                       ws, t_hb, t_pi, mask, aug_hb, aug_pi, aug_at, bnum);
    hipLaunchKernelGGL(k_rsum, dim3(32), dim3(64), 0, stream, ws);
    hipLaunchKernelGGL(k_fused, dim3(16, 32), dim3(256), 0, stream,
                       ws, t_hb, t_pi, mask, aug_hb, aug_pi, aug_at, bnum, attn);
    hipLaunchKernelGGL(k_out, dim3(8, 32), dim3(256), 0, stream,
                       ws, wo_w, wo_b, outp);
}

// Round 3
// 312.235 us; speedup vs baseline: 1.5326x; 1.2557x over previous
//
#include <hip/hip_runtime.h>
#include <math.h>

#define NS 1024
#define DM 512
#define NH 8
#define DEPTH 64

// ws offsets (floats). ctx partials alias qh/kh (dead after k_sumexp).
#define OFF_QH   0
#define OFF_KH   2097152
#define OFF_VH   4194304
#define OFF_CTX0 0
#define OFF_CTX1 2097152
#define OFF_PART 6291456
#define OFF_SINV (OFF_PART + 2048)

// swizzle for Es transpose-scatter: keeps scalar stores at 2 lanes/bank
#define ESW(row, col) ((col) ^ ((((row) >> 3) & 7) << 2))

// ---------------- QKV projection: X(4096x512)@W(512x512)+b -> split heads
// 128x128 tile, BK=32, 8x8/thread, 33.8KB LDS (4 blocks/CU)
__global__ __launch_bounds__(256, 4) void k_proj(
    const float* __restrict__ q, const float* __restrict__ k, const float* __restrict__ v,
    const float* __restrict__ wq, const float* __restrict__ bq,
    const float* __restrict__ wk, const float* __restrict__ bk,
    const float* __restrict__ wv, const float* __restrict__ bv,
    float* __restrict__ ws)
{
    const float *X, *W, *bias; float* out;
    if (blockIdx.z == 0)      { X=q; W=wq; bias=bq; out=ws+OFF_QH; }
    else if (blockIdx.z == 1) { X=k; W=wk; bias=bk; out=ws+OFF_KH; }
    else                      { X=v; W=wv; bias=bv; out=ws+OFF_VH; }

    __shared__ float As[32][132];   // [k][m]
    __shared__ float Bs[32][132];   // [k][n]
    const int tid = threadIdx.x, tx = tid & 15, ty = tid >> 4;
    const int n0 = blockIdx.x * 128, m0 = blockIdx.y * 128;

    float acc[8][8] = {};
    for (int kk = 0; kk < DM; kk += 32) {
        #pragma unroll
        for (int l = 0; l < 4; ++l) {
            const int idx = tid + l*256;
            const int m = idx >> 3, c4 = idx & 7;
            const float4 f = *(const float4*)(X + (size_t)(m0+m)*DM + kk + c4*4);
            As[c4*4+0][m]=f.x; As[c4*4+1][m]=f.y; As[c4*4+2][m]=f.z; As[c4*4+3][m]=f.w;
        }
        #pragma unroll
        for (int l = 0; l < 4; ++l) {
            const int idx = tid + l*256;
            const int r = idx >> 5, c4 = idx & 31;
            *(float4*)&Bs[r][c4*4] = *(const float4*)(W + (size_t)(kk+r)*DM + n0 + c4*4);
        }
        __syncthreads();
        #pragma unroll
        for (int kq = 0; kq < 32; ++kq) {
            const float4 a0 = *(const float4*)&As[kq][ty*4];
            const float4 a1 = *(const float4*)&As[kq][64+ty*4];
            const float4 b0 = *(const float4*)&Bs[kq][tx*4];
            const float4 b1 = *(const float4*)&Bs[kq][64+tx*4];
            const float av[8] = {a0.x,a0.y,a0.z,a0.w,a1.x,a1.y,a1.z,a1.w};
            const float bw[8] = {b0.x,b0.y,b0.z,b0.w,b1.x,b1.y,b1.z,b1.w};
            #pragma unroll
            for (int i = 0; i < 8; ++i)
                #pragma unroll
                for (int j = 0; j < 8; ++j)
                    acc[i][j] = fmaf(av[i], bw[j], acc[i][j]);
        }
        __syncthreads();
    }
    #pragma unroll
    for (int jb = 0; jb < 2; ++jb) {
        const int h = (n0 >> 6) + jb;
        const float4 b4 = *(const float4*)(bias + n0 + jb*64 + tx*4);
        #pragma unroll
        for (int i = 0; i < 8; ++i) {
            const int m = m0 + (i>>2)*64 + ty*4 + (i&3);
            const int bb = m >> 10, s = m & 1023;
            float4 o;
            o.x = acc[i][jb*4+0]+b4.x; o.y = acc[i][jb*4+1]+b4.y;
            o.z = acc[i][jb*4+2]+b4.z; o.w = acc[i][jb*4+3]+b4.w;
            *(float4*)(out + (((size_t)(bb*NH + h))*NS + s)*DEPTH + tx*4) = o;
        }
    }
}

// ---------------- S = K.Q^T (128x128 tile), e = exp(logits) -> write e + partial sums
__global__ __launch_bounds__(256, 4) void k_sumexp(
    float* __restrict__ ws,
    const float* __restrict__ t_hb, const float* __restrict__ t_pi,
    const float* __restrict__ mask,
    const float* __restrict__ aug_hb, const float* __restrict__ aug_pi,
    const float* __restrict__ aug_at, const int* __restrict__ bnum,
    float* __restrict__ attn)
{
    __shared__ float Ks[32][132];   // [d][i]
    __shared__ float Qs[32][132];   // [d][j]
    __shared__ float red[256];
    const int bh = blockIdx.z, b = bh >> 3;
    const int i0 = blockIdx.y * 128, j0 = blockIdx.x * 128;
    const float* kh = ws + OFF_KH + (size_t)bh*NS*DEPTH;
    const float* qh = ws + OFF_QH + (size_t)bh*NS*DEPTH;
    const int tid = threadIdx.x, tx = tid & 15, ty = tid >> 4;

    float acc[8][8] = {};
    for (int d0 = 0; d0 < DEPTH; d0 += 32) {
        #pragma unroll
        for (int l = 0; l < 4; ++l) {
            const int idx = tid + l*256;
            const int r = idx >> 3, c4 = idx & 7;
            const float4 fk = *(const float4*)(kh + (size_t)(i0+r)*DEPTH + d0 + c4*4);
            Ks[c4*4+0][r]=fk.x; Ks[c4*4+1][r]=fk.y; Ks[c4*4+2][r]=fk.z; Ks[c4*4+3][r]=fk.w;
            const float4 fq = *(const float4*)(qh + (size_t)(j0+r)*DEPTH + d0 + c4*4);
            Qs[c4*4+0][r]=fq.x; Qs[c4*4+1][r]=fq.y; Qs[c4*4+2][r]=fq.z; Qs[c4*4+3][r]=fq.w;
        }
        __syncthreads();
        #pragma unroll
        for (int d = 0; d < 32; ++d) {
            const float4 a0 = *(const float4*)&Ks[d][ty*4];
            const float4 a1 = *(const float4*)&Ks[d][64+ty*4];
            const float4 b0 = *(const float4*)&Qs[d][tx*4];
            const float4 b1 = *(const float4*)&Qs[d][64+tx*4];
            const float av[8] = {a0.x,a0.y,a0.z,a0.w,a1.x,a1.y,a1.z,a1.w};
            const float bw[8] = {b0.x,b0.y,b0.z,b0.w,b1.x,b1.y,b1.z,b1.w};
            #pragma unroll
            for (int i = 0; i < 8; ++i)
                #pragma unroll
                for (int j = 0; j < 8; ++j)
                    acc[i][j] = fmaf(av[i], bw[j], acc[i][j]);
        }
        __syncthreads();
    }

    const int bn = bnum[0];
    const float at = aug_at[bn], hb = aug_hb[bn], pi = aug_pi[bn];
    const float sc_at = 0.125f*at, m_at = -1e9f*at;
    float local = 0.f;
    #pragma unroll
    for (int i = 0; i < 8; ++i) {
        const int gi = i0 + (i>>2)*64 + ty*4 + (i&3);
        const size_t mrow = ((size_t)b*NS + gi)*NS;
        const size_t trow = (size_t)gi*NS;
        const size_t arow = ((size_t)bh*NS + gi)*NS;
        #pragma unroll
        for (int cb = 0; cb < 2; ++cb) {
            const int gj = j0 + cb*64 + tx*4;
            const float4 m4 = *(const float4*)(mask + mrow + gj);
            const float4 h4 = *(const float4*)(t_hb + trow + gj);
            const float4 p4 = *(const float4*)(t_pi + trow + gj);
            float4 e4;
            e4.x = __expf(fmaf(acc[i][cb*4+0], sc_at, fmaf(m4.x, m_at, fmaf(hb, h4.x, pi*p4.x))));
            e4.y = __expf(fmaf(acc[i][cb*4+1], sc_at, fmaf(m4.y, m_at, fmaf(hb, h4.y, pi*p4.y))));
            e4.z = __expf(fmaf(acc[i][cb*4+2], sc_at, fmaf(m4.z, m_at, fmaf(hb, h4.z, pi*p4.z))));
            e4.w = __expf(fmaf(acc[i][cb*4+3], sc_at, fmaf(m4.w, m_at, fmaf(hb, h4.w, pi*p4.w))));
            *(float4*)(attn + arow + gj) = e4;
            local += (e4.x + e4.y) + (e4.z + e4.w);
        }
    }
    red[tid] = local;
    __syncthreads();
    for (int s2 = 128; s2 > 0; s2 >>= 1) {
        if (tid < s2) red[tid] += red[tid + s2];
        __syncthreads();
    }
    if (tid == 0) ws[OFF_PART + bh*64 + blockIdx.y*8 + blockIdx.x] = red[0];
}

// ---------------- reduce 64 partials per (b,h) -> 1/sum
__global__ __launch_bounds__(64) void k_rsum(float* __restrict__ ws)
{
    float v = ws[OFF_PART + blockIdx.x*64 + threadIdx.x];
    #pragma unroll
    for (int o = 32; o > 0; o >>= 1) v += __shfl_down(v, o);
    if (threadIdx.x == 0) ws[OFF_SINV + blockIdx.x] = 1.0f / v;
}

// ---------------- k_pv: read e, write attn=e*inv, ctx_partial = (e*inv)@V
// block: 128 i-rows x 64 d, j-range 512 (jh half), j-tiles of 64
__global__ __launch_bounds__(256, 4) void k_pv(
    float* __restrict__ ws, float* __restrict__ attn)
{
    __shared__ float Es[64][132];   // [j][i], swizzled
    __shared__ float Vs[64][68];    // [j][d]
    const int jh = blockIdx.x, bh = blockIdx.z, b = bh >> 3, h = bh & 7;
    const int i0 = blockIdx.y * 128;
    const float* vh = ws + OFF_VH + (size_t)bh*NS*DEPTH;
    const float inv = ws[OFF_SINV + bh];
    float* pctx = ws + (jh ? OFF_CTX1 : OFF_CTX0);
    const int tid = threadIdx.x, tx = tid & 15, ty = tid >> 4;

    float acc[8][4] = {};
    for (int jt = 0; jt < 8; ++jt) {
        const int j0 = jh*512 + jt*64;
        #pragma unroll
        for (int l = 0; l < 8; ++l) {
            const int idx = tid + l*256;
            const int r = idx >> 4;        // i row 0..127
            const int c4 = idx & 15;       // j group
            float* ap = attn + ((size_t)bh*NS + i0 + r)*NS + j0 + c4*4;
            float4 e4 = *(const float4*)ap;
            e4.x *= inv; e4.y *= inv; e4.z *= inv; e4.w *= inv;
            *(float4*)ap = e4;             // final normalized attn
            const int r0 = c4*4;
            Es[r0+0][ESW(r0+0, r)] = e4.x;
            Es[r0+1][ESW(r0+1, r)] = e4.y;
            Es[r0+2][ESW(r0+2, r)] = e4.z;
            Es[r0+3][ESW(r0+3, r)] = e4.w;
        }
        #pragma unroll
        for (int l = 0; l < 4; ++l) {
            const int idx = tid + l*256;
            const int r = idx >> 4, d4 = idx & 15;
            *(float4*)&Vs[r][d4*4] = *(const float4*)(vh + (size_t)(j0+r)*DEPTH + d4*4);
        }
        __syncthreads();
        #pragma unroll
        for (int jj = 0; jj < 64; ++jj) {
            const int sw = ((jj >> 3) & 7) << 2;
            const float4 a0 = *(const float4*)&Es[jj][(ty*4) ^ sw];
            const float4 a1 = *(const float4*)&Es[jj][64 + ((ty*4) ^ sw)];
            const float4 vv = *(const float4*)&Vs[jj][tx*4];
            const float av[8] = {a0.x,a0.y,a0.z,a0.w,a1.x,a1.y,a1.z,a1.w};
            const float vw[4] = {vv.x,vv.y,vv.z,vv.w};
            #pragma unroll
            for (int i = 0; i < 8; ++i)
                #pragma unroll
                for (int d = 0; d < 4; ++d)
                    acc[i][d] = fmaf(av[i], vw[d], acc[i][d]);
        }
        __syncthreads();
    }
    #pragma unroll
    for (int i = 0; i < 8; ++i) {
        const int gi = i0 + (i>>2)*64 + ty*4 + (i&3);
        float4 o;
        o.x = acc[i][0]; o.y = acc[i][1]; o.z = acc[i][2]; o.w = acc[i][3];
        *(float4*)(pctx + ((size_t)b*NS + gi)*DM + h*DEPTH + tx*4) = o;
    }
}

// ---------------- out = (ctx0+ctx1)(4096x512) @ wo + b
__global__ __launch_bounds__(256, 4) void k_out(
    const float* __restrict__ ws_c, const float* __restrict__ wo,
    const float* __restrict__ bo, float* __restrict__ outp)
{
    __shared__ float As[32][132];
    __shared__ float Bs[32][132];
    const int tid = threadIdx.x, tx = tid & 15, ty = tid >> 4;
    const int n0 = blockIdx.x * 128, m0 = blockIdx.y * 128;
    const float* c0 = ws_c + OFF_CTX0;
    const float* c1 = ws_c + OFF_CTX1;

    float acc[8][8] = {};
    for (int kk = 0; kk < DM; kk += 32) {
        #pragma unroll
        for (int l = 0; l < 4; ++l) {
            const int idx = tid + l*256;
            const int m = idx >> 3, c4 = idx & 7;
            const size_t off = (size_t)(m0+m)*DM + kk + c4*4;
            const float4 f0 = *(const float4*)(c0 + off);
            const float4 f1 = *(const float4*)(c1 + off);
            As[c4*4+0][m]=f0.x+f1.x; As[c4*4+1][m]=f0.y+f1.y;
            As[c4*4+2][m]=f0.z+f1.z; As[c4*4+3][m]=f0.w+f1.w;
        }
        #pragma unroll
        for (int l = 0; l < 4; ++l) {
            const int idx = tid + l*256;
            const int r = idx >> 5, c4 = idx & 31;
            *(float4*)&Bs[r][c4*4] = *(const float4*)(wo + (size_t)(kk+r)*DM + n0 + c4*4);
        }
        __syncthreads();
        #pragma unroll
        for (int kq = 0; kq < 32; ++kq) {
            const float4 a0 = *(const float4*)&As[kq][ty*4];
            const float4 a1 = *(const float4*)&As[kq][64+ty*4];
            const float4 b0 = *(const float4*)&Bs[kq][tx*4];
            const float4 b1 = *(const float4*)&Bs[kq][64+tx*4];
            const float av[8] = {a0.x,a0.y,a0.z,a0.w,a1.x,a1.y,a1.z,a1.w};
            const float bw[8] = {b0.x,b0.y,b0.z,b0.w,b1.x,b1.y,b1.z,b1.w};
            #pragma unroll
            for (int i = 0; i < 8; ++i)
                #pragma unroll
                for (int j = 0; j < 8; ++j)
                    acc[i][j] = fmaf(av[i], bw[j], acc[i][j]);
        }
        __syncthreads();
    }
    #pragma unroll
    for (int jb = 0; jb < 2; ++jb) {
        const float4 b4 = *(const float4*)(bo + n0 + jb*64 + tx*4);
        #pragma unroll
        for (int i = 0; i < 8; ++i) {
            const int m = m0 + (i>>2)*64 + ty*4 + (i&3);
            float4 o;
            o.x = acc[i][jb*4+0]+b4.x; o.y = acc[i][jb*4+1]+b4.y;
            o.z = acc[i][jb*4+2]+b4.z; o.w = acc[i][jb*4+3]+b4.w;
            *(float4*)(outp + (size_t)m*DM + n0 + jb*64 + tx*4) = o;
        }
    }
}

extern "C" void kernel_launch(void* const* d_in, const int* in_sizes, int n_in,
                              void* d_out, int out_size, void* d_ws, size_t ws_size,
                              hipStream_t stream)
{
    const float* v    = (const float*)d_in[0];
    const float* q    = (const float*)d_in[1];
    const float* k    = (const float*)d_in[2];
    const float* wq_w = (const float*)d_in[3];
    const float* wq_b = (const float*)d_in[4];
    const float* wk_w = (const float*)d_in[5];
    const float* wk_b = (const float*)d_in[6];
    const float* wv_w = (const float*)d_in[7];
    const float* wv_b = (const float*)d_in[8];
    const float* wo_w = (const float*)d_in[9];
    const float* wo_b = (const float*)d_in[10];
    const float* aug_hb = (const float*)d_in[11];
    const float* aug_pi = (const float*)d_in[12];
    const float* aug_at = (const float*)d_in[13];
    const float* t_hb   = (const float*)d_in[14];
    const float* t_pi   = (const float*)d_in[15];
    const float* mask   = (const float*)d_in[16];
    const int*   bnum   = (const int*)d_in[17];

    float* ws   = (float*)d_ws;
    float* outp = (float*)d_out;
    float* attn = (float*)d_out + (size_t)4*NS*DM;

    hipLaunchKernelGGL(k_proj, dim3(4, 32, 3), dim3(256), 0, stream,
                       q, k, v, wq_w, wq_b, wk_w, wk_b, wv_w, wv_b, ws);
    hipLaunchKernelGGL(k_sumexp, dim3(8, 8, 32), dim3(256), 0, stream,
                       ws, t_hb, t_pi, mask, aug_hb, aug_pi, aug_at, bnum, attn);
    hipLaunchKernelGGL(k_rsum, dim3(32), dim3(64), 0, stream, ws);
    hipLaunchKernelGGL(k_pv, dim3(2, 8, 32), dim3(256), 0, stream, ws, attn);
    hipLaunchKernelGGL(k_out, dim3(4, 32), dim3(256), 0, stream,
                       ws, wo_w, wo_b, outp);
}